// Round 16
// baseline (223.530 us; speedup 1.0000x reference)
//
#include <hip/hip_runtime.h>
#include <stdint.h>

#define NBOX 1024
#define BLK  512

typedef unsigned long long u64;
typedef unsigned int u32;
typedef unsigned short u16;
typedef unsigned char u8;

// ---------- bit-exact IoU (matches numpy f32 op-for-op; _rn blocks FMA contraction) ----------
__device__ __forceinline__ float iou_pair(const float4 lb, float larea,
                                          const float4 pb, float parea) {
    float ix1 = fmaxf(lb.x, pb.x);
    float iy1 = fmaxf(lb.y, pb.y);
    float ix2 = fminf(lb.z, pb.z);
    float iy2 = fminf(lb.w, pb.w);
    float w = fmaxf(__fsub_rn(ix2, ix1), 0.0f);
    float h = fmaxf(__fsub_rn(iy2, iy1), 0.0f);
    float inter = __fmul_rn(w, h);
    float denom = __fsub_rn(__fadd_rn(larea, parea), inter);
    return inter / denom;
}

__device__ __forceinline__ u64 umax64(u64 a, u64 b) { return a > b ? a : b; }

// ---------- 64-lane u64 max butterfly via DPP; result valid in lane 63 ----------
__device__ __forceinline__ u64 dpp_max64(u64 v) {
    unsigned lo, hi; u64 o;
#define DPP_STEP(CTRL) \
    lo = (unsigned)__builtin_amdgcn_update_dpp(0, (int)(unsigned)(v & 0xffffffffull), CTRL, 0xf, 0xf, true); \
    hi = (unsigned)__builtin_amdgcn_update_dpp(0, (int)(unsigned)(v >> 32),           CTRL, 0xf, 0xf, true); \
    o = (((u64)hi) << 32) | lo; \
    if (o > v) v = o;
    DPP_STEP(0x111) DPP_STEP(0x112) DPP_STEP(0x114)
    DPP_STEP(0x118) DPP_STEP(0x142) DPP_STEP(0x143)
#undef DPP_STEP
    return v;
}

__device__ __forceinline__ u64 readlane64(u64 v, int l) {
    unsigned lo = (unsigned)__builtin_amdgcn_readlane((int)(unsigned)(v & 0xffffffffull), l);
    unsigned hi = (unsigned)__builtin_amdgcn_readlane((int)(unsigned)(v >> 32), l);
    return (((u64)hi) << 32) | lo;
}

// =====================================================================================
// Init A (1024 blocks): rowlist[b][0..7] = sorted top-8 (valbits<<10)|col, desc (val,col).
// =====================================================================================
__global__ void __launch_bounds__(64) init_rowlist(const float* __restrict__ labels,
                                                   const float* __restrict__ preds,
                                                   u64* __restrict__ rowlist) {
    const int b = blockIdx.x;
    const int lane = threadIdx.x;
    float4 lb = ((const float4*)labels)[b];
    float la = __fmul_rn(__fsub_rn(lb.z, lb.x), __fsub_rn(lb.w, lb.y));
    u32 vb[16];
    #pragma unroll
    for (int j = 0; j < 16; ++j) {
        int c = lane + (j << 6);
        float4 pb = ((const float4*)preds)[c];
        float pa = __fmul_rn(__fsub_rn(pb.z, pb.x), __fsub_rn(pb.w, pb.y));
        vb[j] = __float_as_uint(iou_pair(lb, la, pb, pa));
    }
    u32 used = 0;
    for (int it = 0; it < 8; ++it) {
        u64 best = 0;
        #pragma unroll
        for (int j = 0; j < 16; ++j) {
            if (!((used >> j) & 1u)) {
                u64 p = ((u64)vb[j] << 10) | (u32)(lane + (j << 6));
                best = umax64(best, p);
            }
        }
        best = dpp_max64(best);
        u64 bm = readlane64(best, 63);
        if ((bm >> 10) == 0ull) bm = 0;
        if (lane == 0) rowlist[(b << 3) + it] = bm;
        if (bm && (int)(bm & 63) == lane) used |= 1u << ((bm >> 6) & 15);
    }
}

// =====================================================================================
// Init B (1024 blocks): collist[c][0..7] = sorted top-8 (valbits<<10)|label, desc.
// =====================================================================================
__global__ void __launch_bounds__(64) init_collist(const float* __restrict__ labels,
                                                   const float* __restrict__ preds,
                                                   u64* __restrict__ collist) {
    const int c = blockIdx.x;
    const int lane = threadIdx.x;
    float4 pc = ((const float4*)preds)[c];
    float pa = __fmul_rn(__fsub_rn(pc.z, pc.x), __fsub_rn(pc.w, pc.y));
    u32 vb[16];
    #pragma unroll
    for (int j = 0; j < 16; ++j) {
        int L = lane + (j << 6);
        float4 lb = ((const float4*)labels)[L];
        float la = __fmul_rn(__fsub_rn(lb.z, lb.x), __fsub_rn(lb.w, lb.y));
        vb[j] = __float_as_uint(iou_pair(lb, la, pc, pa));
    }
    u32 used = 0;
    for (int it = 0; it < 8; ++it) {
        u64 best = 0;
        #pragma unroll
        for (int j = 0; j < 16; ++j) {
            if (!((used >> j) & 1u)) {
                u64 p = ((u64)vb[j] << 10) | (u32)(lane + (j << 6));
                best = umax64(best, p);
            }
        }
        best = dpp_max64(best);
        u64 bm = readlane64(best, 63);
        if ((bm >> 10) == 0ull) bm = 0;
        if (lane == 0) collist[(c << 3) + it] = bm;
        if (bm && (int)(bm & 63) == lane) used |= 1u << ((bm >> 6) & 15);
    }
}

// =====================================================================================
// Main: 8-wave (512-thread) parallel greedy; 2 elements/thread; register col lists
//   with branchless unrolled walks; global row lists (cold path); exact fallbacks.
// =====================================================================================
__global__ void __launch_bounds__(BLK, 1)
rounds_kernel(const float* __restrict__ preds,
              const float* __restrict__ labels,
              const u64* __restrict__ rowlist,   // may be null (fallback-only mode)
              const u64* __restrict__ collist,   // may be null
              float* __restrict__ out) {
    __shared__ float4 pred4s[NBOX];
    __shared__ float4 lab4s[NBOX];
    __shared__ float  parea_s[NBOX];
    __shared__ float  larea_s[NBOX];
    __shared__ u64    rkey[NBOX];      // (val<<10)|col ; 0 = dead/locked
    __shared__ u64    colbest[NBOX];   // suitor: (val<<10)|label
    __shared__ u16    dest_s[NBOX];
    __shared__ u16    perm_s[NBOX];
    __shared__ u8     seenc[NBOX];
    __shared__ u8     lockedl[NBOX];
    __shared__ u32    seenw[32];
    __shared__ u32    lockedw[32];
    __shared__ int    ncom[2];
    __shared__ float  fpart[8];

    const int t    = (int)threadIdx.x;   // 0..511
    const int lane = t & 63;
    const int wid  = t >> 6;             // 0..7

    #pragma unroll
    for (int s = 0; s < 2; ++s) {
        int i = t + (s << 9);
        float4 p = ((const float4*)preds)[i];
        float4 L = ((const float4*)labels)[i];
        pred4s[i] = p;
        lab4s[i]  = L;
        parea_s[i] = __fmul_rn(__fsub_rn(p.z, p.x), __fsub_rn(p.w, p.y));
        larea_s[i] = __fmul_rn(__fsub_rn(L.z, L.x), __fsub_rn(L.w, L.y));
        perm_s[i] = (u16)i; dest_s[i] = 0;
        seenc[i] = 0; lockedl[i] = 0;
        rkey[i] = rowlist ? rowlist[i << 3] : 0ull;
        colbest[i] = 0ull;
    }
    if (t < 32) { seenw[t] = 0u; lockedw[t] = 0u; }
    if (t < 2) ncom[t] = 0;
    __syncthreads();

    // register-resident col lists for this thread's 2 cols (static indexing only)
    u32 cvA[8], clA[8], cvB[8], clB[8];
    if (collist) {
        #pragma unroll
        for (int k = 0; k < 8; ++k) {
            u64 e = collist[(t << 3) + k];
            cvA[k] = (u32)(e >> 10); clA[k] = (u32)(e & 1023ull);
            e = collist[((t + 512) << 3) + k];
            cvB[k] = (u32)(e >> 10); clB[k] = (u32)(e & 1023ull);
        }
    } else {
        #pragma unroll
        for (int k = 0; k < 8; ++k) { cvA[k] = clA[k] = cvB[k] = clB[k] = 0; }
    }

    u32 myseen = 0;    // bit (m<<2)|k : col 4*lane+256m+k consumed (fallback scans)
    u32 mylocked = 0;  // bit (m<<2)|k : label 4*lane+256m+k locked
    int rptr0 = rowlist ? 0 : 8;
    int rptr1 = rowlist ? 0 : 8;
    int par = 0;
    const bool havelists = (collist != nullptr);

    auto rebuild_seen = [&]() {
        u32 ms = 0;
        #pragma unroll
        for (int m = 0; m < 4; ++m) {
            u32 w_ = seenw[(lane >> 3) + (m << 3)];
            ms |= ((w_ >> ((lane & 7) << 2)) & 0xFu) << (m << 2);
        }
        myseen = ms;
    };
    auto rebuild_locked = [&]() {
        u32 ml = 0;
        #pragma unroll
        for (int m = 0; m < 4; ++m) {
            u32 w_ = lockedw[(lane >> 3) + (m << 3)];
            ml |= ((w_ >> ((lane & 7) << 2)) & 0xFu) << (m << 2);
        }
        mylocked = ml;
    };

    // exact row scan over unseen cols (tie -> larger col); uniform row; uses myseen
    auto scan_row_exact = [&](int row) -> u64 {
        float4 lbx = lab4s[row];
        float la = larea_s[row];
        u64 best = 0;
        #pragma unroll
        for (int m = 0; m < 4; ++m) {
            #pragma unroll
            for (int k = 0; k < 4; ++k) {
                int cc = 4 * lane + 256 * m + k;
                float v = iou_pair(lbx, la, pred4s[cc], parea_s[cc]);
                u64 p = ((u64)__float_as_uint(v) << 10) | (unsigned)cc;
                if ((myseen >> ((m << 2) | k)) & 1u) p = 0;
                best = umax64(best, p);
            }
        }
        best = dpp_max64(best);
        u64 bm = readlane64(best, 63);
        return (bm >> 10) ? bm : 0ull;
    };

    // exact col scan over unlocked labels + tie flag; uniform col; uses mylocked
    auto scan_col_exact = [&](int c) -> u64 {
        float4 pc = pred4s[c];
        float  pa = parea_s[c];
        u64 best = 0; u32 v1 = 0, v2 = 0;
        #pragma unroll
        for (int m = 0; m < 4; ++m) {
            #pragma unroll
            for (int k = 0; k < 4; ++k) {
                int L = 4 * lane + 256 * m + k;
                float v = iou_pair(lab4s[L], larea_s[L], pc, pa);
                u32 vbb = __float_as_uint(v);
                if ((mylocked >> ((m << 2) | k)) & 1u) vbb = 0;
                if (vbb >= v1) { v2 = v1; v1 = vbb; } else { v2 = (vbb > v2) ? vbb : v2; }
                best = umax64(best, ((u64)vbb << 10) | (unsigned)L);
            }
        }
        best = dpp_max64(best);
        u64 bm = readlane64(best, 63);
        u32 V = (u32)(bm >> 10);
        if (!V) return 0ull;
        u64 b1 = __ballot(v1 == V);
        u64 b2 = __ballot(v2 == V);
        bool tie = (__popcll(b1) >= 2) || (b2 != 0ull);
        return ((u64)V << 32) | (tie ? (1ull << 16) : 0ull) | (bm & 1023ull);
    };

    auto do_commit = [&](int c, int L) {
        seenc[c] = 1; lockedl[L] = 1; rkey[L] = 0ull;
        dest_s[L] = (u16)c; perm_s[c] = (u16)L;
        atomicOr(&seenw[c >> 5], 1u << (c & 31));
        atomicOr(&lockedw[L >> 5], 1u << (L & 31));
        atomicAdd(&ncom[par], 1);
    };

    // branchless col-list walk: commit / defer / mark exact-fallback
    // CV/CL = register arrays (static unrolled access), c = col index, sbv = suitor
#define COLWALK(CV, CL, cidx, sbv, needx) do { \
        if (!havelists) { needx = true; } else { \
            bool lk_[8]; \
            _Pragma("unroll") \
            for (int k = 0; k < 8; ++k) lk_[k] = lockedl[CL[k]]; \
            u32 fm_ = 0; \
            _Pragma("unroll") \
            for (int k = 0; k < 8; ++k) if (CV[k] && !lk_[k]) fm_ |= 1u << k; \
            if (!fm_) { if (CV[7]) needx = true; /* else dead col */ } \
            else { \
                u32 V_ = 0, lab_ = 0; \
                _Pragma("unroll") \
                for (int k = 7; k >= 0; --k) \
                    if ((fm_ >> k) & 1u) { V_ = CV[k]; lab_ = CL[k]; } \
                u32 eq_ = 0; \
                _Pragma("unroll") \
                for (int k = 0; k < 8; ++k) if (CV[k] == V_) eq_ |= 1u << k; \
                bool tie_ = __popc(fm_ & eq_) >= 2; \
                if (!tie_) { \
                    if (CV[7] == V_) needx = true;              /* boundary */ \
                    else if ((u32)((sbv) & 1023ull) == lab_) do_commit((cidx), (int)lab_); \
                } /* tie -> defer */ \
            } \
        } } while (0)

    if (!rowlist) {   // no-ws fallback init: exact row maxes (myseen == 0 here)
        for (int row = wid; row < NBOX; row += 8) {
            u64 r = scan_row_exact(row);
            if (lane == 0) rkey[row] = r;
        }
        __syncthreads();
    }

    // ---- initial suitor push (both slots) ----
    #pragma unroll
    for (int s = 0; s < 2; ++s) {
        u64 k = rkey[t + (s << 9)];
        if (k) atomicMax((unsigned long long*)&colbest[k & 1023ull],
                         ((k >> 10) << 10) | (u64)(unsigned)(t + (s << 9)));
    }
    __syncthreads();

    for (int round = 0; round < 4096; ++round) {
        par = round & 1;

        // ---- P1: per-col register-list walk -> commit / defer / exact fallback ----
        {
            u64 sb0 = colbest[t];       colbest[t] = 0ull;
            u64 sb1 = colbest[t + 512]; colbest[t + 512] = 0ull;
            bool ne0 = false, ne1 = false;
            if (sb0) COLWALK(cvA, clA, t, sb0, ne0);
            if (sb1) COLWALK(cvB, clB, t + 512, sb1, ne1);
            u64 bal = __ballot(ne0);
            if (bal) {
                rebuild_locked();
                while (bal) {
                    int l = (int)__ffsll(bal) - 1; bal &= bal - 1;
                    int c = (wid << 6) | l;
                    u64 o = scan_col_exact(c);
                    u64 sbl = readlane64(sb0, l);
                    if (lane == 0) {
                        if ((o >> 32) && !((o >> 16) & 1ull) &&
                            (u32)(o & 1023ull) == (u32)(sbl & 1023ull))
                            do_commit(c, (int)(o & 1023ull));
                    }
                }
            }
            bal = __ballot(ne1);
            if (bal) {
                rebuild_locked();
                while (bal) {
                    int l = (int)__ffsll(bal) - 1; bal &= bal - 1;
                    int c = 512 + ((wid << 6) | l);
                    u64 o = scan_col_exact(c);
                    u64 sbl = readlane64(sb1, l);
                    if (lane == 0) {
                        if ((o >> 32) && !((o >> 16) & 1ull) &&
                            (u32)(o & 1023ull) == (u32)(sbl & 1023ull))
                            do_commit(c, (int)(o & 1023ull));
                    }
                }
            }
        }
        __syncthreads();

        // ---- P2: termination, per-row list promotion (global lists), push ----
        const int cnt = ncom[par];
        if (t == 0) ncom[par ^ 1] = 0;
        if (cnt == 0) break;                      // no commits -> perm final
        {
            bool ns0 = false, ns1 = false;
            #pragma unroll
            for (int s = 0; s < 2; ++s) {
                int row = t + (s << 9);
                int rp = s ? rptr1 : rptr0;
                bool needscan = false;
                u64 k = rkey[row];
                if (k && seenc[k & 1023ull]) {
                    if (rp >= 8) {
                        needscan = true;
                    } else {
                        int i = rp; u64 nk = 0;
                        for (; i < 8; ++i) {
                            u64 e = rowlist[(row << 3) + i];
                            if ((e >> 10) == 0ull) break;        // dead (zero-kill)
                            if (!seenc[e & 1023ull]) { nk = e; break; }
                        }
                        if (i < 8) { rkey[row] = nk; rp = i; }
                        else { rp = 8; needscan = true; }
                    }
                }
                if (s) { rptr1 = rp; ns1 = needscan; } else { rptr0 = rp; ns0 = needscan; }
            }
            u64 bal = __ballot(ns0);
            if (bal) {
                rebuild_seen();
                while (bal) {
                    int l = (int)__ffsll(bal) - 1; bal &= bal - 1;
                    int row = (wid << 6) | l;
                    u64 r = scan_row_exact(row);
                    if (lane == 0) rkey[row] = r;
                }
            }
            bal = __ballot(ns1);
            if (bal) {
                rebuild_seen();
                while (bal) {
                    int l = (int)__ffsll(bal) - 1; bal &= bal - 1;
                    int row = 512 + ((wid << 6) | l);
                    u64 r = scan_row_exact(row);
                    if (lane == 0) rkey[row] = r;
                }
            }
            #pragma unroll
            for (int s = 0; s < 2; ++s) {
                int row = t + (s << 9);
                u64 k2 = rkey[row];
                if (k2) atomicMax((unsigned long long*)&colbest[k2 & 1023ull],
                                  ((k2 >> 10) << 10) | (u64)(unsigned)row);
            }
        }
        __syncthreads();
    }

    // ---- one-time displacement chase for open rows ----
    #pragma unroll
    for (int s = 0; s < 2; ++s) {
        int i = t + (s << 9);
        if (!seenc[i]) {
            int l = i;
            while (lockedl[l]) l = (int)dest_s[l];
            perm_s[i] = (u16)l;
        }
    }
    __syncthreads();

    // ---- loss = mean |labels[perm] - predictions| ----
    {
        float sum = 0.0f;
        #pragma unroll
        for (int s = 0; s < 2; ++s) {
            int i = t + (s << 9);
            float4 lb = lab4s[perm_s[i]];
            float4 pb = pred4s[i];
            sum += fabsf(lb.x - pb.x) + fabsf(lb.y - pb.y) +
                   fabsf(lb.z - pb.z) + fabsf(lb.w - pb.w);
        }
        for (int off = 32; off > 0; off >>= 1) sum += __shfl_xor(sum, off, 64);
        if (lane == 0) fpart[wid] = sum;
        __syncthreads();
        if (t == 0) {
            float s = 0.0f;
            for (int w = 0; w < 8; ++w) s += fpart[w];
            out[0] = s * (1.0f / 4096.0f);
        }
    }
}

extern "C" void kernel_launch(void* const* d_in, const int* in_sizes, int n_in,
                              void* d_out, int out_size, void* d_ws, size_t ws_size,
                              hipStream_t stream) {
    const float* preds  = (const float*)d_in[0];   // predictions [1024,4]
    const float* labels = (const float*)d_in[1];   // labels      [1024,4]
    float* out = (float*)d_out;

    const size_t list_b = (size_t)NBOX * 8 * sizeof(u64);   // 64 KB each
    if (d_ws && ws_size >= 2 * list_b) {
        u64* rl = (u64*)d_ws;
        u64* cl = rl + NBOX * 8;
        init_rowlist<<<NBOX, 64, 0, stream>>>(labels, preds, rl);
        init_collist<<<NBOX, 64, 0, stream>>>(labels, preds, cl);
        rounds_kernel<<<1, BLK, 0, stream>>>(preds, labels, rl, cl, out);
    } else {
        rounds_kernel<<<1, BLK, 0, stream>>>(preds, labels, nullptr, nullptr, out);
    }
}

// Round 17
// 223.502 us; speedup vs baseline: 1.0001x; 1.0001x over previous
//
#include <hip/hip_runtime.h>
#include <stdint.h>

#define NBOX 1024
#define BLK  512

typedef unsigned long long u64;
typedef unsigned int u32;
typedef unsigned short u16;
typedef unsigned char u8;

// ---------- bit-exact IoU (matches numpy f32 op-for-op; _rn blocks FMA contraction) ----------
__device__ __forceinline__ float iou_pair(const float4 lb, float larea,
                                          const float4 pb, float parea) {
    float ix1 = fmaxf(lb.x, pb.x);
    float iy1 = fmaxf(lb.y, pb.y);
    float ix2 = fminf(lb.z, pb.z);
    float iy2 = fminf(lb.w, pb.w);
    float w = fmaxf(__fsub_rn(ix2, ix1), 0.0f);
    float h = fmaxf(__fsub_rn(iy2, iy1), 0.0f);
    float inter = __fmul_rn(w, h);
    float denom = __fsub_rn(__fadd_rn(larea, parea), inter);
    return inter / denom;
}

__device__ __forceinline__ u64 umax64(u64 a, u64 b) { return a > b ? a : b; }

// ---------- 64-lane u64 max butterfly via DPP; result valid in lane 63 ----------
__device__ __forceinline__ u64 dpp_max64(u64 v) {
    unsigned lo, hi; u64 o;
#define DPP_STEP(CTRL) \
    lo = (unsigned)__builtin_amdgcn_update_dpp(0, (int)(unsigned)(v & 0xffffffffull), CTRL, 0xf, 0xf, true); \
    hi = (unsigned)__builtin_amdgcn_update_dpp(0, (int)(unsigned)(v >> 32),           CTRL, 0xf, 0xf, true); \
    o = (((u64)hi) << 32) | lo; \
    if (o > v) v = o;
    DPP_STEP(0x111) DPP_STEP(0x112) DPP_STEP(0x114)
    DPP_STEP(0x118) DPP_STEP(0x142) DPP_STEP(0x143)
#undef DPP_STEP
    return v;
}

__device__ __forceinline__ u64 readlane64(u64 v, int l) {
    unsigned lo = (unsigned)__builtin_amdgcn_readlane((int)(unsigned)(v & 0xffffffffull), l);
    unsigned hi = (unsigned)__builtin_amdgcn_readlane((int)(unsigned)(v >> 32), l);
    return (((u64)hi) << 32) | lo;
}

// =====================================================================================
// Init A (1024 blocks): rowlist[b][0..7] = sorted top-8 (valbits<<10)|col, desc (val,col).
// =====================================================================================
__global__ void __launch_bounds__(64) init_rowlist(const float* __restrict__ labels,
                                                   const float* __restrict__ preds,
                                                   u64* __restrict__ rowlist) {
    const int b = blockIdx.x;
    const int lane = threadIdx.x;
    float4 lb = ((const float4*)labels)[b];
    float la = __fmul_rn(__fsub_rn(lb.z, lb.x), __fsub_rn(lb.w, lb.y));
    u32 vb[16];
    #pragma unroll
    for (int j = 0; j < 16; ++j) {
        int c = lane + (j << 6);
        float4 pb = ((const float4*)preds)[c];
        float pa = __fmul_rn(__fsub_rn(pb.z, pb.x), __fsub_rn(pb.w, pb.y));
        vb[j] = __float_as_uint(iou_pair(lb, la, pb, pa));
    }
    u32 used = 0;
    for (int it = 0; it < 8; ++it) {
        u64 best = 0;
        #pragma unroll
        for (int j = 0; j < 16; ++j) {
            if (!((used >> j) & 1u)) {
                u64 p = ((u64)vb[j] << 10) | (u32)(lane + (j << 6));
                best = umax64(best, p);
            }
        }
        best = dpp_max64(best);
        u64 bm = readlane64(best, 63);
        if ((bm >> 10) == 0ull) bm = 0;
        if (lane == 0) rowlist[(b << 3) + it] = bm;
        if (bm && (int)(bm & 63) == lane) used |= 1u << ((bm >> 6) & 15);
    }
}

// =====================================================================================
// Init B (1024 blocks): collist[c][0..7] = sorted top-8 (valbits<<10)|label, desc.
// =====================================================================================
__global__ void __launch_bounds__(64) init_collist(const float* __restrict__ labels,
                                                   const float* __restrict__ preds,
                                                   u64* __restrict__ collist) {
    const int c = blockIdx.x;
    const int lane = threadIdx.x;
    float4 pc = ((const float4*)preds)[c];
    float pa = __fmul_rn(__fsub_rn(pc.z, pc.x), __fsub_rn(pc.w, pc.y));
    u32 vb[16];
    #pragma unroll
    for (int j = 0; j < 16; ++j) {
        int L = lane + (j << 6);
        float4 lb = ((const float4*)labels)[L];
        float la = __fmul_rn(__fsub_rn(lb.z, lb.x), __fsub_rn(lb.w, lb.y));
        vb[j] = __float_as_uint(iou_pair(lb, la, pc, pa));
    }
    u32 used = 0;
    for (int it = 0; it < 8; ++it) {
        u64 best = 0;
        #pragma unroll
        for (int j = 0; j < 16; ++j) {
            if (!((used >> j) & 1u)) {
                u64 p = ((u64)vb[j] << 10) | (u32)(lane + (j << 6));
                best = umax64(best, p);
            }
        }
        best = dpp_max64(best);
        u64 bm = readlane64(best, 63);
        if ((bm >> 10) == 0ull) bm = 0;
        if (lane == 0) collist[(c << 3) + it] = bm;
        if (bm && (int)(bm & 63) == lane) used |= 1u << ((bm >> 6) & 15);
    }
}

// =====================================================================================
// Main: 8-wave (512-thread) parallel greedy; ALL lists + row keys in registers;
//   hot-path state reads only the 32-word seen/locked bitmaps; exact fallbacks cold.
// =====================================================================================
__global__ void __launch_bounds__(BLK, 1)
rounds_kernel(const float* __restrict__ preds,
              const float* __restrict__ labels,
              const u64* __restrict__ rowlist,   // may be null (fallback-only mode)
              const u64* __restrict__ collist,   // may be null
              float* __restrict__ out) {
    __shared__ float4 pred4s[NBOX];
    __shared__ float4 lab4s[NBOX];
    __shared__ float  parea_s[NBOX];
    __shared__ float  larea_s[NBOX];
    __shared__ u64    colbest[NBOX];   // suitor: (val<<10)|label
    __shared__ u16    dest_s[NBOX];
    __shared__ u16    perm_s[NBOX];
    __shared__ u32    seenw[32];       // col-consumed bitmap
    __shared__ u32    lockedw[32];     // label-locked bitmap
    __shared__ int    ncom[2];
    __shared__ float  fpart[8];

    const int t    = (int)threadIdx.x;   // 0..511
    const int lane = t & 63;
    const int wid  = t >> 6;             // 0..7

    #pragma unroll
    for (int s = 0; s < 2; ++s) {
        int i = t + (s << 9);
        float4 p = ((const float4*)preds)[i];
        float4 L = ((const float4*)labels)[i];
        pred4s[i] = p;
        lab4s[i]  = L;
        parea_s[i] = __fmul_rn(__fsub_rn(p.z, p.x), __fsub_rn(p.w, p.y));
        larea_s[i] = __fmul_rn(__fsub_rn(L.z, L.x), __fsub_rn(L.w, L.y));
        perm_s[i] = (u16)i; dest_s[i] = 0;
        colbest[i] = 0ull;
    }
    if (t < 32) { seenw[t] = 0u; lockedw[t] = 0u; }
    if (t < 2) ncom[t] = 0;
    __syncthreads();

    const bool havelists = (collist != nullptr);

    // register-resident lists for this thread's 2 cols and 2 rows (static indexing only)
    u32 cvA[8], clA[8], cvB[8], clB[8];
    u32 rvA[8], rcA[8], rvB[8], rcB[8];
    if (havelists) {
        #pragma unroll
        for (int k = 0; k < 8; ++k) {
            u64 e = collist[(t << 3) + k];
            cvA[k] = (u32)(e >> 10); clA[k] = (u32)(e & 1023ull);
            e = collist[((t + 512) << 3) + k];
            cvB[k] = (u32)(e >> 10); clB[k] = (u32)(e & 1023ull);
            e = rowlist[(t << 3) + k];
            rvA[k] = (u32)(e >> 10); rcA[k] = (u32)(e & 1023ull);
            e = rowlist[((t + 512) << 3) + k];
            rvB[k] = (u32)(e >> 10); rcB[k] = (u32)(e & 1023ull);
        }
    } else {
        #pragma unroll
        for (int k = 0; k < 8; ++k) {
            cvA[k] = clA[k] = cvB[k] = clB[k] = 0;
            rvA[k] = rcA[k] = rvB[k] = rcB[k] = 0;
        }
    }

    u64 rk0 = havelists ? (((u64)rvA[0] << 10) | rcA[0]) : 0ull;   // 0 if rvA[0]==0
    u64 rk1 = havelists ? (((u64)rvB[0] << 10) | rcB[0]) : 0ull;
    if ((rk0 >> 10) == 0ull) rk0 = 0;
    if ((rk1 >> 10) == 0ull) rk1 = 0;
    int rptr0 = havelists ? 0 : 8;
    int rptr1 = havelists ? 0 : 8;

    u32 myseen = 0;    // bit (m<<2)|k : col 4*lane+256m+k consumed (fallback scans)
    u32 mylocked = 0;  // bit (m<<2)|k : label 4*lane+256m+k locked
    int par = 0;

    auto rebuild_seen = [&]() {
        u32 ms = 0;
        #pragma unroll
        for (int m = 0; m < 4; ++m) {
            u32 w_ = seenw[(lane >> 3) + (m << 3)];
            ms |= ((w_ >> ((lane & 7) << 2)) & 0xFu) << (m << 2);
        }
        myseen = ms;
    };
    auto rebuild_locked = [&]() {
        u32 ml = 0;
        #pragma unroll
        for (int m = 0; m < 4; ++m) {
            u32 w_ = lockedw[(lane >> 3) + (m << 3)];
            ml |= ((w_ >> ((lane & 7) << 2)) & 0xFu) << (m << 2);
        }
        mylocked = ml;
    };

    // exact row scan over unseen cols (tie -> larger col); uniform row; uses myseen
    auto scan_row_exact = [&](int row) -> u64 {
        float4 lbx = lab4s[row];
        float la = larea_s[row];
        u64 best = 0;
        #pragma unroll
        for (int m = 0; m < 4; ++m) {
            #pragma unroll
            for (int k = 0; k < 4; ++k) {
                int cc = 4 * lane + 256 * m + k;
                float v = iou_pair(lbx, la, pred4s[cc], parea_s[cc]);
                u64 p = ((u64)__float_as_uint(v) << 10) | (unsigned)cc;
                if ((myseen >> ((m << 2) | k)) & 1u) p = 0;
                best = umax64(best, p);
            }
        }
        best = dpp_max64(best);
        u64 bm = readlane64(best, 63);
        return (bm >> 10) ? bm : 0ull;
    };

    // exact col scan over unlocked labels + tie flag; uniform col; uses mylocked
    auto scan_col_exact = [&](int c) -> u64 {
        float4 pc = pred4s[c];
        float  pa = parea_s[c];
        u64 best = 0; u32 v1 = 0, v2 = 0;
        #pragma unroll
        for (int m = 0; m < 4; ++m) {
            #pragma unroll
            for (int k = 0; k < 4; ++k) {
                int L = 4 * lane + 256 * m + k;
                float v = iou_pair(lab4s[L], larea_s[L], pc, pa);
                u32 vbb = __float_as_uint(v);
                if ((mylocked >> ((m << 2) | k)) & 1u) vbb = 0;
                if (vbb >= v1) { v2 = v1; v1 = vbb; } else { v2 = (vbb > v2) ? vbb : v2; }
                best = umax64(best, ((u64)vbb << 10) | (unsigned)L);
            }
        }
        best = dpp_max64(best);
        u64 bm = readlane64(best, 63);
        u32 V = (u32)(bm >> 10);
        if (!V) return 0ull;
        u64 b1 = __ballot(v1 == V);
        u64 b2 = __ballot(v2 == V);
        bool tie = (__popcll(b1) >= 2) || (b2 != 0ull);
        return ((u64)V << 32) | (tie ? (1ull << 16) : 0ull) | (bm & 1023ull);
    };

    auto do_commit = [&](int c, int L) {
        dest_s[L] = (u16)c; perm_s[c] = (u16)L;
        atomicOr(&seenw[c >> 5], 1u << (c & 31));
        atomicOr(&lockedw[L >> 5], 1u << (L & 31));
        atomicAdd(&ncom[par], 1);
    };

    // branchless col-list walk: commit / defer / mark exact-fallback (bitmap reads)
#define COLWALK(CV, CL, cidx, sbv, needx) do { \
        if (!havelists) { needx = true; } else { \
            bool lk_[8]; \
            _Pragma("unroll") \
            for (int k = 0; k < 8; ++k) \
                lk_[k] = (lockedw[CL[k] >> 5] >> (CL[k] & 31)) & 1u; \
            u32 fm_ = 0; \
            _Pragma("unroll") \
            for (int k = 0; k < 8; ++k) if (CV[k] && !lk_[k]) fm_ |= 1u << k; \
            if (!fm_) { if (CV[7]) needx = true; /* else dead col */ } \
            else { \
                u32 V_ = 0, lab_ = 0; \
                _Pragma("unroll") \
                for (int k = 7; k >= 0; --k) \
                    if ((fm_ >> k) & 1u) { V_ = CV[k]; lab_ = CL[k]; } \
                u32 eq_ = 0; \
                _Pragma("unroll") \
                for (int k = 0; k < 8; ++k) if (CV[k] == V_) eq_ |= 1u << k; \
                bool tie_ = __popc(fm_ & eq_) >= 2; \
                if (!tie_) { \
                    if (CV[7] == V_) needx = true;              /* boundary */ \
                    else if ((u32)((sbv) & 1023ull) == lab_) do_commit((cidx), (int)lab_); \
                } /* tie -> defer */ \
            } \
        } } while (0)

    // branchless row promotion via register list + seen bitmap
#define PROMOTE(RK, RP, RV, RC, rowv, needs) do { \
        if (RK) { \
            if ((lockedw[(rowv) >> 5] >> ((rowv) & 31)) & 1u) { RK = 0; } \
            else { \
                u32 c_ = (u32)(RK & 1023ull); \
                if ((seenw[c_ >> 5] >> (c_ & 31)) & 1u) { \
                    if (RP >= 8) { needs = true; } \
                    else { \
                        u32 vm_ = 0, zm_ = 0; \
                        _Pragma("unroll") \
                        for (int k = 0; k < 8; ++k) { \
                            bool sn_ = (seenw[RC[k] >> 5] >> (RC[k] & 31)) & 1u; \
                            if (RV[k] == 0) zm_ |= 1u << k; \
                            else if (!sn_) vm_ |= 1u << k; \
                        } \
                        vm_ &= ~((1u << RP) - 1); \
                        u32 lim_ = zm_ ? ((1u << (__ffs(zm_) - 1)) - 1) : 0xFFu; \
                        u32 cand_ = vm_ & lim_; \
                        if (cand_) { int k_ = __ffs(cand_) - 1; \
                            RK = ((u64)RV[k_] << 10) | RC[k_]; RP = k_; } \
                        else if (zm_) { RK = 0; } \
                        else { RP = 8; needs = true; } \
                    } \
                } \
            } \
        } } while (0)

    if (!havelists) {   // no-ws fallback init: exact row maxes (myseen == 0 here)
        for (int row = wid; row < NBOX; row += 8) {
            u64 r = scan_row_exact(row);
            if (lane == (row & 63) && (row < 512 ? t == row : t == row - 512)) {}
            // assign to owner thread's register
            if ((row & 511) == t) { if (row < 512) rk0 = r; else rk1 = r; }
        }
        __syncthreads();
    }

    // ---- initial suitor push (both slots) ----
    if (rk0) atomicMax((unsigned long long*)&colbest[rk0 & 1023ull],
                       ((rk0 >> 10) << 10) | (u64)(unsigned)t);
    if (rk1) atomicMax((unsigned long long*)&colbest[rk1 & 1023ull],
                       ((rk1 >> 10) << 10) | (u64)(unsigned)(t + 512));
    __syncthreads();

    for (int round = 0; round < 4096; ++round) {
        par = round & 1;

        // ---- P1: per-col register-list walk -> commit / defer / exact fallback ----
        {
            u64 sb0 = colbest[t];       colbest[t] = 0ull;
            u64 sb1 = colbest[t + 512]; colbest[t + 512] = 0ull;
            bool ne0 = false, ne1 = false;
            if (sb0) COLWALK(cvA, clA, t, sb0, ne0);
            if (sb1) COLWALK(cvB, clB, t + 512, sb1, ne1);
            u64 bal = __ballot(ne0);
            if (bal) {
                rebuild_locked();
                while (bal) {
                    int l = (int)__ffsll(bal) - 1; bal &= bal - 1;
                    int c = (wid << 6) | l;
                    u64 o = scan_col_exact(c);
                    u64 sbl = readlane64(sb0, l);
                    if (lane == 0) {
                        if ((o >> 32) && !((o >> 16) & 1ull) &&
                            (u32)(o & 1023ull) == (u32)(sbl & 1023ull))
                            do_commit(c, (int)(o & 1023ull));
                    }
                }
            }
            bal = __ballot(ne1);
            if (bal) {
                rebuild_locked();
                while (bal) {
                    int l = (int)__ffsll(bal) - 1; bal &= bal - 1;
                    int c = 512 + ((wid << 6) | l);
                    u64 o = scan_col_exact(c);
                    u64 sbl = readlane64(sb1, l);
                    if (lane == 0) {
                        if ((o >> 32) && !((o >> 16) & 1ull) &&
                            (u32)(o & 1023ull) == (u32)(sbl & 1023ull))
                            do_commit(c, (int)(o & 1023ull));
                    }
                }
            }
        }
        __syncthreads();

        // ---- P2: termination, register-list promotion, fallback scans, push ----
        const int cnt = ncom[par];
        if (t == 0) ncom[par ^ 1] = 0;
        if (cnt == 0) break;                      // no commits -> perm final
        {
            bool ns0 = false, ns1 = false;
            PROMOTE(rk0, rptr0, rvA, rcA, t, ns0);
            PROMOTE(rk1, rptr1, rvB, rcB, t + 512, ns1);
            u64 bal = __ballot(ns0);
            if (bal) {
                rebuild_seen();
                while (bal) {
                    int l = (int)__ffsll(bal) - 1; bal &= bal - 1;
                    int row = (wid << 6) | l;
                    u64 r = scan_row_exact(row);
                    if (lane == l) rk0 = r;
                }
            }
            bal = __ballot(ns1);
            if (bal) {
                rebuild_seen();
                while (bal) {
                    int l = (int)__ffsll(bal) - 1; bal &= bal - 1;
                    int row = 512 + ((wid << 6) | l);
                    u64 r = scan_row_exact(row);
                    if (lane == l) rk1 = r;
                }
            }
            if (rk0) atomicMax((unsigned long long*)&colbest[rk0 & 1023ull],
                               ((rk0 >> 10) << 10) | (u64)(unsigned)t);
            if (rk1) atomicMax((unsigned long long*)&colbest[rk1 & 1023ull],
                               ((rk1 >> 10) << 10) | (u64)(unsigned)(t + 512));
        }
        __syncthreads();
    }

    // ---- one-time displacement chase for open rows ----
    #pragma unroll
    for (int s = 0; s < 2; ++s) {
        int i = t + (s << 9);
        if (!((seenw[i >> 5] >> (i & 31)) & 1u)) {
            int l = i;
            while ((lockedw[l >> 5] >> (l & 31)) & 1u) l = (int)dest_s[l];
            perm_s[i] = (u16)l;
        }
    }
    __syncthreads();

    // ---- loss = mean |labels[perm] - predictions| ----
    {
        float sum = 0.0f;
        #pragma unroll
        for (int s = 0; s < 2; ++s) {
            int i = t + (s << 9);
            float4 lb = lab4s[perm_s[i]];
            float4 pb = pred4s[i];
            sum += fabsf(lb.x - pb.x) + fabsf(lb.y - pb.y) +
                   fabsf(lb.z - pb.z) + fabsf(lb.w - pb.w);
        }
        for (int off = 32; off > 0; off >>= 1) sum += __shfl_xor(sum, off, 64);
        if (lane == 0) fpart[wid] = sum;
        __syncthreads();
        if (t == 0) {
            float s = 0.0f;
            for (int w = 0; w < 8; ++w) s += fpart[w];
            out[0] = s * (1.0f / 4096.0f);
        }
    }
}

extern "C" void kernel_launch(void* const* d_in, const int* in_sizes, int n_in,
                              void* d_out, int out_size, void* d_ws, size_t ws_size,
                              hipStream_t stream) {
    const float* preds  = (const float*)d_in[0];   // predictions [1024,4]
    const float* labels = (const float*)d_in[1];   // labels      [1024,4]
    float* out = (float*)d_out;

    const size_t list_b = (size_t)NBOX * 8 * sizeof(u64);   // 64 KB each
    if (d_ws && ws_size >= 2 * list_b) {
        u64* rl = (u64*)d_ws;
        u64* cl = rl + NBOX * 8;
        init_rowlist<<<NBOX, 64, 0, stream>>>(labels, preds, rl);
        init_collist<<<NBOX, 64, 0, stream>>>(labels, preds, cl);
        rounds_kernel<<<1, BLK, 0, stream>>>(preds, labels, rl, cl, out);
    } else {
        rounds_kernel<<<1, BLK, 0, stream>>>(preds, labels, nullptr, nullptr, out);
    }
}